// Round 7
// baseline (505.444 us; speedup 1.0000x reference)
//
#include <hip/hip_runtime.h>
#include <hip/hip_bf16.h>
#include <math.h>

// Problem constants (from reference)
#define LEN_TOT 21760
#define BATCH 2
#define MROWS (BATCH * LEN_TOT)   // 43520
#define DMODEL 256
#define DFFN 1024

typedef unsigned short ushort_t;
typedef __attribute__((ext_vector_type(8))) short short8;
typedef __attribute__((ext_vector_type(4))) float floatx4;
typedef __attribute__((address_space(3))) ushort_t lds_us;
typedef __attribute__((address_space(1))) const ushort_t glb_us;

// fp32 -> bf16 raw bits, round-to-nearest-even
__device__ __forceinline__ ushort_t f2b(float f) {
    unsigned u = __float_as_uint(f);
    unsigned r = (u + 0x7FFFu + ((u >> 16) & 1u)) >> 16;
    return (ushort_t)r;
}

// ---------------------------------------------------------------------------
// Fused weight transpose + fp32->bf16 convert: W[K][N] f32 -> WT[N][K] bf16.
// ---------------------------------------------------------------------------
struct TP {
    const float* s[6];
    ushort_t*    d[6];
    int K[6];
    int N[6];
    int start[7];
};

__global__ __launch_bounds__(256) void transpose_convert(TP tp) {
    __shared__ float tile[32][33];
    int blk = blockIdx.x;
    int seg = 0;
    while (seg < 5 && blk >= tp.start[seg + 1]) seg++;
    int local = blk - tp.start[seg];
    int K = tp.K[seg], N = tp.N[seg];
    int tn = N >> 5;
    int k0 = (local / tn) << 5, n0 = (local % tn) << 5;
    int r = threadIdx.x >> 5, c = threadIdx.x & 31;
    const float* src = tp.s[seg];
    #pragma unroll
    for (int rr = r; rr < 32; rr += 8)
        tile[rr][c] = src[(size_t)(k0 + rr) * N + n0 + c];
    __syncthreads();
    ushort_t* dst = tp.d[seg];
    #pragma unroll
    for (int rr = r; rr < 32; rr += 8)
        dst[(size_t)(n0 + rr) * K + k0 + c] = f2b(tile[c][rr]);
}

// concat qk bias: [bof(256) | bat(128)]
__global__ void bias_cat(const float* __restrict__ a, const float* __restrict__ b,
                         float* __restrict__ o) {
    int t = threadIdx.x;  // 384 threads
    o[t] = (t < 256) ? a[t] : b[t - 256];
}

// ---------------------------------------------------------------------------
// LayerNorm (+ optional pos add) -> bf16 output; optionally also emits
// bf16 copy of the raw input (for the un-normed value path).
// ---------------------------------------------------------------------------
__global__ __launch_bounds__(256) void ln_dual_kernel(
    const float* __restrict__ x, const float* __restrict__ g,
    const float* __restrict__ bb, const float* __restrict__ addv,
    ushort_t* __restrict__ y_bf, ushort_t* __restrict__ x_bf)
{
    int row  = blockIdx.x * 4 + (threadIdx.x >> 6);
    int lane = threadIdx.x & 63;
    size_t base = (size_t)row * DMODEL + lane * 4;
    float4 v = *(const float4*)(x + base);

    float s = v.x + v.y + v.z + v.w;
    #pragma unroll
    for (int o = 32; o; o >>= 1) s += __shfl_xor(s, o, 64);
    float mu = s * (1.0f / 256.0f);

    float d0 = v.x - mu, d1 = v.y - mu, d2 = v.z - mu, d3 = v.w - mu;
    float vs = d0*d0 + d1*d1 + d2*d2 + d3*d3;
    #pragma unroll
    for (int o = 32; o; o >>= 1) vs += __shfl_xor(vs, o, 64);
    float rstd = rsqrtf(vs * (1.0f / 256.0f) + 1e-5f);

    float4 gv = *(const float4*)(g  + lane * 4);
    float4 bv = *(const float4*)(bb + lane * 4);
    float o0 = d0 * rstd * gv.x + bv.x;
    float o1 = d1 * rstd * gv.y + bv.y;
    float o2 = d2 * rstd * gv.z + bv.z;
    float o3 = d3 * rstd * gv.w + bv.w;
    if (addv) {
        float4 av = *(const float4*)(addv + base);
        o0 += av.x; o1 += av.y; o2 += av.z; o3 += av.w;
    }
    ushort4 ob = {f2b(o0), f2b(o1), f2b(o2), f2b(o3)};
    *(ushort4*)(y_bf + base) = ob;
    if (x_bf) {
        ushort4 xb = {f2b(v.x), f2b(v.y), f2b(v.z), f2b(v.w)};
        *(ushort4*)(x_bf + base) = xb;
    }
}

// ---------------------------------------------------------------------------
// bf16 MFMA GEMM v2: C[M,N] = act(A @ B + bias) [+ res]
// A: [M][K] bf16 row-major. Bt: [N][K] bf16 (pre-transposed weight).
// BM=BN=128, BK=64; 256 threads = 4 waves, each wave 4x4 16x16x32 tiles x2 kb.
// Staging: global_load_lds width=16 with XOR seg swizzle phys=seg^(row&7)
// (applied on the GLOBAL source address so the LDS dest stays lane-linear,
//  satisfying the wave-uniform-base constraint). Fragment ds_read_b128 then
// lands 2-way on banks (free) instead of 8/16-way.
// ---------------------------------------------------------------------------
template<int GELU_ACT, int HAS_RES, int OUT_BF16>
__global__ __launch_bounds__(256) void gemm_mfma(
    const ushort_t* __restrict__ A, const ushort_t* __restrict__ Bt,
    const float* __restrict__ bias, const float* __restrict__ res,
    float* __restrict__ C, ushort_t* __restrict__ Cbf,
    int M, int N, int K)
{
    constexpr int BM = 128, BK = 64;
    __shared__ __align__(16) ushort_t As[BM * BK];   // 16 KB
    __shared__ __align__(16) ushort_t Bs[BM * BK];   // 16 KB

    const int tid  = threadIdx.x;
    const int wave = tid >> 6;
    const int lane = tid & 63;
    const int wm = (wave & 1) * 64;
    const int wn = (wave >> 1) * 64;
    const int ml = lane & 15;      // m (A) / n (B) / col (D)
    const int quad = lane >> 4;    // k-block for A/B; row-block for D
    const int m0 = blockIdx.y * BM, n0 = blockIdx.x * BM;
    const int swz = ml & 7;        // fragment-read XOR

    floatx4 acc[4][4] = {};

    for (int k0 = 0; k0 < K; k0 += BK) {
        // stage 16 KB per tile: chunk c = p*256+tid; r=c>>3, sp=c&7, src seg = sp^(r&7)
        #pragma unroll
        for (int p = 0; p < 4; p++) {
            int c = p * 256 + tid;
            int r = c >> 3, sp = c & 7;
            int sl = sp ^ (r & 7);
            __builtin_amdgcn_global_load_lds(
                (glb_us*)(A + (size_t)(m0 + r) * K + k0 + sl * 8),
                (lds_us*)(As + c * 8), 16, 0, 0);
            __builtin_amdgcn_global_load_lds(
                (glb_us*)(Bt + (size_t)(n0 + r) * K + k0 + sl * 8),
                (lds_us*)(Bs + c * 8), 16, 0, 0);
        }
        __syncthreads();

        #pragma unroll
        for (int kb = 0; kb < 2; kb++) {
            const int sA = quad + 4 * kb;      // logical k-seg
            short8 af[4], bfr[4];
            #pragma unroll
            for (int i = 0; i < 4; i++)
                af[i] = *(const short8*)(As + (wm + i * 16 + ml) * BK + (sA ^ swz) * 8);
            #pragma unroll
            for (int j = 0; j < 4; j++)
                bfr[j] = *(const short8*)(Bs + (wn + j * 16 + ml) * BK + (sA ^ swz) * 8);
            #pragma unroll
            for (int i = 0; i < 4; i++)
                #pragma unroll
                for (int j = 0; j < 4; j++)
                    acc[i][j] = __builtin_amdgcn_mfma_f32_16x16x32_bf16(
                        af[i], bfr[j], acc[i][j], 0, 0, 0);
        }
        __syncthreads();
    }

    // Epilogue. D layout: col = lane&15, row = quad*4 + reg.
    if (OUT_BF16) {
        // wave-private 4 KB region, ping-pong 2 KB per i-tile
        ushort_t* pool  = (wave < 2) ? As : Bs;
        ushort_t* wbase = pool + (wave & 1) * 2048;
        const int lr  = lane >> 2;   // 0..15 readback row
        const int sg  = lane & 3;    // readback 16B segment
        #pragma unroll
        for (int i = 0; i < 4; i++) {
            ushort_t* wbuf = wbase + (i & 1) * 1024;
            #pragma unroll
            for (int j = 0; j < 4; j++) {
                float bc = bias[n0 + wn + j * 16 + ml];
                #pragma unroll
                for (int r = 0; r < 4; r++) {
                    float v = acc[i][j][r] + bc;
                    if (GELU_ACT) v = 0.5f * v * (1.0f + erff(v * 0.7071067811865476f));
                    if (HAS_RES)
                        v += res[(size_t)(m0 + wm + i * 16 + quad * 4 + r) * N
                                 + n0 + wn + j * 16 + ml];
                    wbuf[(quad * 4 + r) * 64 + j * 16 + ml] = f2b(v);
                }
            }
            asm volatile("s_waitcnt lgkmcnt(0)" ::: "memory");
            #pragma unroll
            for (int h = 0; h < 2; h++) {
                short8 vv = *(const short8*)(wbuf + lr * 64 + (sg + 4 * h) * 8);
                *(short8*)(Cbf + (size_t)(m0 + wm + i * 16 + lr) * N
                                 + n0 + wn + (sg + 4 * h) * 8) = vv;
            }
        }
    } else {
        #pragma unroll
        for (int j = 0; j < 4; j++) {
            int col = n0 + wn + j * 16 + ml;
            float bc = bias[col];
            #pragma unroll
            for (int i = 0; i < 4; i++) {
                int row = m0 + wm + i * 16 + quad * 4;
                #pragma unroll
                for (int r = 0; r < 4; r++) {
                    float v = acc[i][j][r] + bc;
                    if (GELU_ACT) v = 0.5f * v * (1.0f + erff(v * 0.7071067811865476f));
                    if (HAS_RES) v += res[(size_t)(row + r) * N + col];
                    C[(size_t)(row + r) * N + col] = v;
                }
            }
        }
    }
}

// ---------------------------------------------------------------------------
// Fused softmax + multi-scale deformable bilinear sampling, v4.
// One block per bq (8 heads). Phase 1 (threads 0-127): thread (g=t>>4, i=t&15)
// computes head g / sample i's softmax prob + 4 clamped corner (addr, weight)
// pairs ONCE, stores to LDS. Phase 2: 8 subgroups of 32 lanes = (corner cl,
// channel-quad d4); per sample: 1 ds_read_b64 + 1 uint2 bf16 gather + unpack
// + 4 FMA. Corner reduction via 2 xor-shuffles. value is bf16 (bytes halved).
// ---------------------------------------------------------------------------
__global__ __launch_bounds__(256) void msdeform_kernel(
    const ushort_t* __restrict__ value, const float* __restrict__ qk,
    const float* __restrict__ refp, ushort_t* __restrict__ out_bf)
{
    __shared__ int2 meta[8][16][4];   // [head][sample][corner] = (addr, w_bits)

    const int t  = threadIdx.x;
    const int bq = blockIdx.x;
    const int b  = (bq >= LEN_TOT) ? 1 : 0;

    if (t < 128) {
        int g = t >> 4, i = t & 15;
        // softmax over 16 logits (cols 256..383 of qk row)
        float logit = qk[(size_t)bq * 384 + 256 + g * 16 + i];
        float mx = logit;
        #pragma unroll
        for (int o = 8; o; o >>= 1) mx = fmaxf(mx, __shfl_xor(mx, o, 16));
        float e = __expf(logit - mx);
        float se = e;
        #pragma unroll
        for (int o = 8; o; o >>= 1) se += __shfl_xor(se, o, 16);
        float prob = e / se;

        int lvl = i >> 2;
        int Wl  = 128 >> lvl;
        float Wf = (float)Wl;
        const int ST_[4] = {0, 16384, 20480, 21504};

        float2 off2 = *(const float2*)(qk + (size_t)bq * 384 + g * 32 + i * 2);
        float2 ref2 = ((const float2*)refp)[(size_t)bq * 4 + lvl];
        float xs = fmaf(ref2.x, Wf, off2.x) - 0.5f;
        float ys = fmaf(ref2.y, Wf, off2.y) - 0.5f;
        float xf = floorf(xs), yf = floorf(ys);
        int x0 = (int)xf, y0 = (int)yf;
        float wx = xs - xf, wy = ys - yf;
        float wx1 = 1.0f - wx, wy1 = 1.0f - wy;

        bool vx0 = (x0 >= 0) & (x0 < Wl);
        bool vx1 = (x0 + 1 >= 0) & (x0 + 1 < Wl);
        bool vy0 = (y0 >= 0) & (y0 < Wl);
        bool vy1 = (y0 + 1 >= 0) & (y0 + 1 < Wl);
        int cx0 = min(max(x0, 0), Wl - 1);
        int cx1 = min(max(x0 + 1, 0), Wl - 1);
        int cy0 = min(max(y0, 0), Wl - 1);
        int cy1 = min(max(y0 + 1, 0), Wl - 1);

        int vbase = b * LEN_TOT + ST_[lvl];
        int i00 = (vbase + cy0 * Wl + cx0) * 256 + g * 32;
        int i01 = (vbase + cy0 * Wl + cx1) * 256 + g * 32;
        int i10 = (vbase + cy1 * Wl + cx0) * 256 + g * 32;
        int i11 = (vbase + cy1 * Wl + cx1) * 256 + g * 32;
        float w00 = (vx0 && vy0) ? prob * wx1 * wy1 : 0.0f;
        float w01 = (vx1 && vy0) ? prob * wx  * wy1 : 0.0f;
        float w10 = (vx0 && vy1) ? prob * wx1 * wy  : 0.0f;
        float w11 = (vx1 && vy1) ? prob * wx  * wy  : 0.0f;

        *(int4*)&meta[g][i][0] = make_int4(i00, __float_as_int(w00),
                                           i01, __float_as_int(w01));
        *(int4*)&meta[g][i][2] = make_int4(i10, __float_as_int(w10),
                                           i11, __float_as_int(w11));
    }
    __syncthreads();

    const int g  = t >> 5;          // head
    const int l  = t & 31;
    const int cl = l >> 3;          // corner
    const int d4 = l & 7;           // channel quad
    float ax = 0.0f, ay = 0.0f, az = 0.0f, aw = 0.0f;
    #pragma unroll
    for (int s = 0; s < 16; s++) {
        int2 mw = meta[g][s][cl];
        float w = __int_as_float(mw.y);
        uint2 u = *(const uint2*)(value + mw.x + (d4 << 2));
        float f0 = __uint_as_float(u.x << 16);
        float f1 = __uint_as_float(u.x & 0xFFFF0000u);
        float f2 = __uint_as_float(u.y << 16);
        float f3 = __uint_as_float(u.y & 0xFFFF0000u);
        ax = fmaf(w, f0, ax); ay = fmaf(w, f1, ay);
        az = fmaf(w, f2, az); aw = fmaf(w, f3, aw);
    }
    // reduce over the 4 corners (lanes xor 8, xor 16 within the 32-lane subgroup)
    ax += __shfl_xor(ax, 8, 32);  ay += __shfl_xor(ay, 8, 32);
    az += __shfl_xor(az, 8, 32);  aw += __shfl_xor(aw, 8, 32);
    ax += __shfl_xor(ax, 16, 32); ay += __shfl_xor(ay, 16, 32);
    az += __shfl_xor(az, 16, 32); aw += __shfl_xor(aw, 16, 32);

    if (l < 8) {
        ushort4 o = {f2b(ax), f2b(ay), f2b(az), f2b(aw)};
        *(ushort4*)(out_bf + ((size_t)bq * 8 + g) * 32 + (d4 << 2)) = o;
    }
}

// ---------------------------------------------------------------------------
// kernel_launch — workspace plan (byte offsets, peak ~135.2 MB):
//   A [0,      22.28M) q_bf            -> h0_bf (step 7+)
//   B [22.28M, 44.56M) src_bf          -> sampled (step 5+)
//   C [44.56M, 66.85M) value_bf (bf16) -> dead after step 5
//   D [66.85M,133.69M) qk f32 [M,384]  -> dead after step 5
//   src2 f32 [89.13M, 133.69M)  (tail of D; D dead when written at step 6)
//   h1_bf [44.56M, 89.13M) = C + head of D, chunked FFN (Mc=M/2) — no overlap
//   G [133.69M, ~135.2M) transposed weights + qk bias
// ---------------------------------------------------------------------------
extern "C" void kernel_launch(void* const* d_in, const int* in_sizes, int n_in,
                              void* d_out, int out_size, void* d_ws, size_t ws_size,
                              hipStream_t stream)
{
    const float* src  = (const float*)d_in[0];
    const float* pos  = (const float*)d_in[1];
    const float* refp = (const float*)d_in[2];
    const float* n1g = (const float*)d_in[5];
    const float* n1b = (const float*)d_in[6];
    const float* n2g = (const float*)d_in[7];
    const float* n2b = (const float*)d_in[8];
    const float* Wv  = (const float*)d_in[9];
    const float* bv  = (const float*)d_in[10];
    const float* Wof = (const float*)d_in[11];
    const float* bof = (const float*)d_in[12];
    const float* Wat = (const float*)d_in[13];
    const float* bat = (const float*)d_in[14];
    const float* Wo  = (const float*)d_in[15];
    const float* bo  = (const float*)d_in[16];
    const float* Wf1 = (const float*)d_in[17];
    const float* bf1 = (const float*)d_in[18];
    const float* Wf2 = (const float*)d_in[19];
    const float* bf2 = (const float*)d_in[20];
    float* out = (float*)d_out;

    char* ws = (char*)d_ws;
    const int M  = MROWS;               // 43520
    const int Mc = M / 2;               // 21760
    const size_t SZ_BF = (size_t)M * 256 * 2;   // 22,282,240

    ushort_t* q_bf     = (ushort_t*)(ws);
    ushort_t* src_bf   = (ushort_t*)(ws + SZ_BF);
    ushort_t* value_bf = (ushort_t*)(ws + 2 * SZ_BF);
    float*    qkb      = (float*)   (ws + 3 * SZ_BF);          // [M,384] f32
    float*    src2     = (float*)   (ws + 4 * SZ_BF);          // tail of qk region
    ushort_t* h0_bf    = q_bf;
    ushort_t* sampled  = src_bf;
    ushort_t* h1_bf    = value_bf;       // [Mc,1024] bf16 = 44.56 MB (C + D-head)
    char* wtp = ws + 3 * SZ_BF + (size_t)M * 384 * 4;
    ushort_t* WvT  = (ushort_t*)(wtp);
    ushort_t* WofT = WvT  + 256 * 256;   // WofT/WatT adjacent => combined [384][256]
    ushort_t* WatT = WofT + 256 * 256;
    ushort_t* WoT  = WatT + 256 * 128;
    ushort_t* Wf1T = WoT  + 256 * 256;
    ushort_t* Wf2T = Wf1T + 256 * 1024;
    float*    bqk  = (float*)(Wf2T + 1024 * 256);   // concat bias [384]

    // 0) transpose+convert all weights to [N][K] bf16; concat qk bias
    TP tp;
    tp.s[0] = Wv;  tp.d[0] = WvT;  tp.K[0] = 256;  tp.N[0] = 256;
    tp.s[1] = Wof; tp.d[1] = WofT; tp.K[1] = 256;  tp.N[1] = 256;
    tp.s[2] = Wat; tp.d[2] = WatT; tp.K[2] = 256;  tp.N[2] = 128;
    tp.s[3] = Wo;  tp.d[3] = WoT;  tp.K[3] = 256;  tp.N[3] = 256;
    tp.s[4] = Wf1; tp.d[4] = Wf1T; tp.K[4] = 256;  tp.N[4] = 1024;
    tp.s[5] = Wf2; tp.d[5] = Wf2T; tp.K[5] = 1024; tp.N[5] = 256;
    tp.start[0] = 0;   tp.start[1] = 64;  tp.start[2] = 128;
    tp.start[3] = 160; tp.start[4] = 224; tp.start[5] = 480; tp.start[6] = 736;
    transpose_convert<<<736, 256, 0, stream>>>(tp);
    bias_cat<<<1, 384, 0, stream>>>(bof, bat, bqk);

    // 1) q_bf = bf16(LN1(src) + pos); src_bf = bf16(src)
    ln_dual_kernel<<<M / 4, 256, 0, stream>>>(src, n1g, n1b, pos, q_bf, src_bf);
    // 2) value_bf = bf16(src_bf @ Wv + bv)
    gemm_mfma<0, 0, 1><<<dim3(2, M / 128), 256, 0, stream>>>(
        src_bf, WvT, bv, nullptr, nullptr, value_bf, M, 256, 256);
    // 3) qk = q_bf @ [Wof|Wat] + [bof|bat]   (fp32, N=384)
    gemm_mfma<0, 0, 0><<<dim3(3, M / 128), 256, 0, stream>>>(
        q_bf, WofT, bqk, nullptr, qkb, nullptr, M, 384, 256);
    // 4) fused softmax + sampling -> sampled (bf16; value_bf/qk dead after)
    msdeform_kernel<<<M, 256, 0, stream>>>(value_bf, qkb, refp, sampled);
    // 5) src2 = sampled @ Wo + bo + src  (fp32, into dead qk tail)
    gemm_mfma<0, 1, 0><<<dim3(2, M / 128), 256, 0, stream>>>(
        sampled, WoT, bo, src, src2, nullptr, M, 256, 256);
    // 6) h0_bf = bf16(LN2(src2))
    ln_dual_kernel<<<M / 4, 256, 0, stream>>>(src2, n2g, n2b, nullptr, h0_bf, nullptr);
    // 7/8) FFN in 2 row-chunks: h1 = bf16(gelu(h0@Wf1+bf1)); out = h1@Wf2+bf2+src2
    for (int c = 0; c < 2; c++) {
        const ushort_t* h0c = h0_bf + (size_t)c * Mc * 256;
        const float*    s2c = src2  + (size_t)c * Mc * 256;
        float*          oc  = out   + (size_t)c * Mc * 256;
        gemm_mfma<1, 0, 1><<<dim3(8, Mc / 128), 256, 0, stream>>>(
            h0c, Wf1T, bf1, nullptr, nullptr, h1_bf, Mc, 1024, 256);
        gemm_mfma<0, 1, 0><<<dim3(2, Mc / 128), 256, 0, stream>>>(
            h1_bf, Wf2T, bf2, s2c, oc, nullptr, Mc, 256, 1024);
    }
}